// Round 12
// baseline (132.679 us; speedup 1.0000x reference)
//
#include <hip/hip_runtime.h>
#include <hip/hip_bf16.h>
#include <math.h>

#define B_ 2
#define S_ 4096
#define D_ 256
#define H_ 8
#define DFF_ 1024
#define DK_ 32

typedef __attribute__((ext_vector_type(8))) short short8;
typedef __attribute__((ext_vector_type(4))) float f32x4;
typedef __attribute__((ext_vector_type(16))) float f32x16;
typedef __attribute__((ext_vector_type(4))) int int4v;

__device__ __forceinline__ unsigned short f2bf(float f) {
  unsigned int u = __builtin_bit_cast(unsigned int, f);
  u += 0x7FFFu + ((u >> 16) & 1u);
  return (unsigned short)(u >> 16);
}

__device__ __forceinline__ float bf2f(unsigned short s) {
  unsigned int u = ((unsigned int)s) << 16;
  return __builtin_bit_cast(float, u);
}

__device__ __forceinline__ short8 u32x4_to_s8(unsigned int a, unsigned int b,
                                              unsigned int c, unsigned int d) {
  int4v v = {(int)a, (int)b, (int)c, (int)d};
  return __builtin_bit_cast(short8, v);
}

// ---------------- fused prep: weight transpose+convert, x->bf16 --------------
__global__ __launch_bounds__(256) void k_prepw(
    const float* __restrict__ Wq, const float* __restrict__ Wk,
    const float* __restrict__ Wv, const float* __restrict__ Wo,
    const float* __restrict__ W1, const float* __restrict__ W2,
    const float* __restrict__ bq, const float* __restrict__ bk,
    const float* __restrict__ bv, const float* __restrict__ x,
    unsigned short* __restrict__ WqkvT, unsigned short* __restrict__ WoT,
    unsigned short* __restrict__ W1T, unsigned short* __restrict__ W2T,
    float* __restrict__ bqkv, unsigned short* __restrict__ xb) {
  const float k2 = 0.25500525551f;  // log2(e)/sqrt(DK)
  int bx = blockIdx.x, t = threadIdx.x;
  if (bx < 768) {
    int which = bx >> 8;
    int i = ((bx & 255) << 8) | t;
    const float* W = (which == 0) ? Wq : (which == 1) ? Wk : Wv;
    int n = i >> 8, k = i & 255;
    float v = W[k * 256 + n] * ((which == 0) ? k2 : 1.0f);
    WqkvT[(size_t)(which * 256 + n) * 256 + k] = f2bf(v);
  } else if (bx < 1024) {
    int i = ((bx - 768) << 8) | t;
    int n = i >> 8, k = i & 255;
    WoT[i] = f2bf(Wo[k * 256 + n]);
  } else if (bx < 2048) {
    int i = ((bx - 1024) << 8) | t;
    int n = i >> 8, k = i & 255;
    W1T[i] = f2bf(W1[k * 1024 + n]);
  } else if (bx < 3072) {
    int i = ((bx - 2048) << 8) | t;
    int n = i >> 10, k = i & 1023;
    W2T[i] = f2bf(W2[k * 256 + n]);
  } else if (bx < 3075) {
    int i = ((bx - 3072) << 8) | t;
    if (i < 768) bqkv[i] = (i < 256) ? bq[i] * k2 : (i < 512) ? bk[i - 256] : bv[i - 512];
  } else {
    int i = (bx - 3075) * 2048 + t * 8;
    f32x4 f0 = *(const f32x4*)(x + i);
    f32x4 f1 = *(const f32x4*)(x + i + 4);
    short8 o;
#pragma unroll
    for (int e = 0; e < 4; e++) { o[e] = (short)f2bf(f0[e]); o[e + 4] = (short)f2bf(f1[e]); }
    *(short8*)(xb + i) = o;
  }
}

// ---------------- QKV GEMM with fragment-scatter epilogue --------------------
__global__ __launch_bounds__(256) void k_gemmqkv(const unsigned short* __restrict__ A,
                                                 const unsigned short* __restrict__ Bt,
                                                 const float* __restrict__ bias,
                                                 unsigned short* __restrict__ qb,
                                                 unsigned short* __restrict__ kpk,
                                                 unsigned short* __restrict__ vpk) {
  const int K = 256;
  __shared__ unsigned short Al[128][40];
  __shared__ unsigned short Bl[64][40];
  const int tid = threadIdx.x;
  const int wid = tid >> 6, lane = tid & 63;
  const int lhi = lane >> 4, llo = lane & 15;
  const int rowbase = wid * 32;
  const int bm = blockIdx.x, bn = blockIdx.y;

  f32x4 zero = {0.f, 0.f, 0.f, 0.f};
  f32x4 acc[2][4];
#pragma unroll
  for (int m = 0; m < 2; m++)
#pragma unroll
    for (int n = 0; n < 4; n++) acc[m][n] = zero;

  const int r0 = tid >> 2, c8 = (tid & 3) * 8;
  const unsigned short* A16a = A + (size_t)(bm * 128 + r0) * K + c8;
  const unsigned short* A16b = A + (size_t)(bm * 128 + r0 + 64) * K + c8;
  const unsigned short* Brow0 = Bt + (size_t)(bn * 64 + r0) * K + c8;

  for (int kb = 0; kb < K; kb += 32) {
    __syncthreads();
    *(short8*)&Al[r0][c8] = *(const short8*)(A16a + kb);
    *(short8*)&Al[r0 + 64][c8] = *(const short8*)(A16b + kb);
    *(short8*)&Bl[r0][c8] = *(const short8*)(Brow0 + kb);
    __syncthreads();
    short8 af[2], bf[4];
#pragma unroll
    for (int m = 0; m < 2; m++) af[m] = *(const short8*)&Al[rowbase + m * 16 + llo][lhi * 8];
#pragma unroll
    for (int n = 0; n < 4; n++) bf[n] = *(const short8*)&Bl[n * 16 + llo][lhi * 8];
#pragma unroll
    for (int m = 0; m < 2; m++)
#pragma unroll
      for (int n = 0; n < 4; n++)
        acc[m][n] = __builtin_amdgcn_mfma_f32_16x16x32_bf16(af[m], bf[n], acc[m][n], 0, 0, 0);
  }

  const int which = bn >> 2;  // 0=Q, 1=K, 2=V
#pragma unroll
  for (int m = 0; m < 2; m++)
#pragma unroll
    for (int n = 0; n < 4; n++)
#pragma unroll
      for (int r = 0; r < 4; r++) {
        int row = bm * 128 + rowbase + m * 16 + lhi * 4 + r;
        int gcol = bn * 64 + n * 16 + llo;
        int col0 = gcol - which * 256;
        float v = acc[m][n][r] + bias[gcol];
        unsigned short bv = f2bf(v);
        int t = row & (S_ - 1), b = row >> 12;
        int h = col0 >> 5;
        if (which == 0) {
          qb[(size_t)row * 256 + col0] = bv;
        } else if (which == 1) {
          int c5 = col0 & 31, jj = (c5 >> 4) & 1, hik = (c5 >> 3) & 1, e = c5 & 7;
          int tile = t >> 6, i = (t >> 5) & 1, l31k = t & 31;
          size_t addr = (((size_t)(b * 8 + h) * 64 + tile) * 4 + i * 2 + jj) * 512 +
                        (hik * 32 + l31k) * 8 + e;
          kpk[addr] = bv;
        } else {
          int d = col0 & 31;
          int x5 = t >> 6, j = (t >> 3) & 7, kk = t & 7;
          size_t addr = (((size_t)(b * 8 + h) * 64 + x5) * 4 + (j >> 1)) * 512 +
                        ((j & 1) * 32 + d) * 8 + kk;
          vpk[addr] = bv;
        }
      }
}

// ---------------- bf16 GEMM (FFN1): C = GELU(A @ Bt^T + bias), bf16 out ------
__global__ __launch_bounds__(256) void k_gemm1(const unsigned short* __restrict__ A,
                                               const unsigned short* __restrict__ Bt,
                                               const float* __restrict__ bias,
                                               unsigned short* __restrict__ Cout,
                                               int M, int N, int K) {
  __shared__ unsigned short Al[128][40];
  __shared__ unsigned short Bl[128][40];
  const int tid = threadIdx.x;
  const int wid = tid >> 6, lane = tid & 63;
  const int lhi = lane >> 4, llo = lane & 15;
  const int wr = wid >> 1, wc = wid & 1;
  const int rowbase = wr * 64, colbase = wc * 64;
  const int bm = blockIdx.x, bn = blockIdx.y;

  f32x4 zero = {0.f, 0.f, 0.f, 0.f};
  f32x4 acc[4][4];
#pragma unroll
  for (int m = 0; m < 4; m++)
#pragma unroll
    for (int n = 0; n < 4; n++) acc[m][n] = zero;

  const int r0 = tid >> 2, c8 = (tid & 3) * 8;
  const unsigned short* A16a = A + (size_t)(bm * 128 + r0) * K + c8;
  const unsigned short* A16b = A + (size_t)(bm * 128 + r0 + 64) * K + c8;
  const unsigned short* Brow0 = Bt + (size_t)(bn * 128 + r0) * K + c8;
  const unsigned short* Brow1 = Bt + (size_t)(bn * 128 + r0 + 64) * K + c8;

  for (int kb = 0; kb < K; kb += 32) {
    __syncthreads();
    *(short8*)&Al[r0][c8] = *(const short8*)(A16a + kb);
    *(short8*)&Al[r0 + 64][c8] = *(const short8*)(A16b + kb);
    *(short8*)&Bl[r0][c8] = *(const short8*)(Brow0 + kb);
    *(short8*)&Bl[r0 + 64][c8] = *(const short8*)(Brow1 + kb);
    __syncthreads();
    short8 af[4], bf[4];
#pragma unroll
    for (int m = 0; m < 4; m++) af[m] = *(const short8*)&Al[rowbase + m * 16 + llo][lhi * 8];
#pragma unroll
    for (int n = 0; n < 4; n++) bf[n] = *(const short8*)&Bl[colbase + n * 16 + llo][lhi * 8];
#pragma unroll
    for (int m = 0; m < 4; m++)
#pragma unroll
      for (int n = 0; n < 4; n++)
        acc[m][n] = __builtin_amdgcn_mfma_f32_16x16x32_bf16(af[m], bf[n], acc[m][n], 0, 0, 0);
  }

#pragma unroll
  for (int m = 0; m < 4; m++)
#pragma unroll
    for (int n = 0; n < 4; n++)
#pragma unroll
      for (int r = 0; r < 4; r++) {
        int row = bm * 128 + rowbase + m * 16 + lhi * 4 + r;
        int col = bn * 128 + colbase + n * 16 + llo;
        float v = acc[m][n][r] + bias[col];
        v = 0.5f * v * (1.0f + erff(v * 0.70710678118f));
        Cout[(size_t)row * N + col] = f2bf(v);
      }
}

// ---------------- GEMM + residual + LayerNorm fused, split-K-2 ---------------
template <int BASE16, int OUT32>
__global__ __launch_bounds__(512) void k_gemmln(const unsigned short* __restrict__ A,
                                                const unsigned short* __restrict__ Bt,
                                                const float* __restrict__ bias,
                                                const void* __restrict__ base,
                                                const float* __restrict__ alpha,
                                                const float* __restrict__ g,
                                                const float* __restrict__ be,
                                                void* __restrict__ y, int K) {
  __shared__ unsigned short Al[2][32][40];
  __shared__ unsigned short Bl[2][256][40];
  __shared__ float psum[32][4], psq[32][4];
  float* partial = (float*)&Bl[0][0][0];

  const int tid = threadIdx.x;
  const int w = tid >> 6, lane = tid & 63;
  const int kh = w >> 2, wc = w & 3;
  const int lhi = lane >> 4, llo = lane & 15;
  const int row0 = blockIdx.x * 32;
  const int Kh = K >> 1;

  f32x4 zero = {0.f, 0.f, 0.f, 0.f};
  f32x4 acc[2][4];
#pragma unroll
  for (int m = 0; m < 2; m++)
#pragma unroll
    for (int n = 0; n < 4; n++) acc[m][n] = zero;

  for (int kb = 0; kb < Kh; kb += 32) {
    __syncthreads();
    if (tid < 256) {
      int kh2 = tid >> 7, ra = (tid >> 2) & 31, ca = (tid & 3) * 8;
      *(short8*)&Al[kh2][ra][ca] =
          *(const short8*)(A + (size_t)(row0 + ra) * K + kh2 * Kh + kb + ca);
    }
#pragma unroll
    for (int s = 0; s < 4; s++) {
      int c = tid + s * 512;
      int kh2 = c >> 10, rb = (c >> 2) & 255, cb = (c & 3) * 8;
      *(short8*)&Bl[kh2][rb][cb] =
          *(const short8*)(Bt + (size_t)rb * K + kh2 * Kh + kb + cb);
    }
    __syncthreads();
    short8 af[2], bf[4];
#pragma unroll
    for (int m = 0; m < 2; m++) af[m] = *(const short8*)&Al[kh][m * 16 + llo][lhi * 8];
#pragma unroll
    for (int n = 0; n < 4; n++)
      bf[n] = *(const short8*)&Bl[kh][wc * 64 + n * 16 + llo][lhi * 8];
#pragma unroll
    for (int m = 0; m < 2; m++)
#pragma unroll
      for (int n = 0; n < 4; n++)
        acc[m][n] = __builtin_amdgcn_mfma_f32_16x16x32_bf16(af[m], bf[n], acc[m][n], 0, 0, 0);
  }

  __syncthreads();
  if (kh == 1) {
#pragma unroll
    for (int m = 0; m < 2; m++)
#pragma unroll
      for (int n = 0; n < 4; n++)
#pragma unroll
        for (int r = 0; r < 4; r++) {
          int lrow = m * 16 + lhi * 4 + r;
          int col = wc * 64 + n * 16 + llo;
          partial[lrow * 256 + col] = acc[m][n][r];
        }
  }
  __syncthreads();

  const float a = alpha[0];
  const unsigned short* b16 = (const unsigned short*)base;
  const float* b32 = (const float*)base;

  if (kh == 0) {
#pragma unroll
    for (int m = 0; m < 2; m++)
#pragma unroll
      for (int r = 0; r < 4; r++) {
        int lrow = m * 16 + lhi * 4 + r;
        size_t grow = (size_t)(row0 + lrow);
        float s = 0.f, q = 0.f;
#pragma unroll
        for (int n = 0; n < 4; n++) {
          int col = wc * 64 + n * 16 + llo;
          float v = acc[m][n][r] + partial[lrow * 256 + col] + bias[col];
          float xb = BASE16 ? bf2f(b16[grow * 256 + col]) : b32[grow * 256 + col];
          float rr = fmaf(a, v, xb);
          acc[m][n][r] = rr;
          s += rr;
          q = fmaf(rr, rr, q);
        }
#pragma unroll
        for (int off = 1; off < 16; off <<= 1) {
          s += __shfl_xor(s, off);
          q += __shfl_xor(q, off);
        }
        if (llo == 0) { psum[lrow][wc] = s; psq[lrow][wc] = q; }
      }
  }
  __syncthreads();

  if (kh == 0) {
#pragma unroll
    for (int m = 0; m < 2; m++)
#pragma unroll
      for (int r = 0; r < 4; r++) {
        int lrow = m * 16 + lhi * 4 + r;
        size_t grow = (size_t)(row0 + lrow);
        float S = psum[lrow][0] + psum[lrow][1] + psum[lrow][2] + psum[lrow][3];
        float Q = psq[lrow][0] + psq[lrow][1] + psq[lrow][2] + psq[lrow][3];
        float mu = S * (1.0f / 256.0f);
        float var = Q * (1.0f / 256.0f) - mu * mu;
        float rs = rsqrtf(var + 1e-5f);
#pragma unroll
        for (int n = 0; n < 4; n++) {
          int col = wc * 64 + n * 16 + llo;
          float o = (acc[m][n][r] - mu) * rs * g[col] + be[col];
          if (OUT32) ((float*)y)[grow * 256 + col] = o;
          else ((unsigned short*)y)[grow * 256 + col] = f2bf(o);
        }
      }
  }
}

// ---------------- flash attention: 8 waves = 4 q-tiles x 2 key-halves --------
// Round-12 change: prologue wave-skew (s_sleep) to break intra-SIMD phase
// lockstep -- no-max softmax is order-independent so the skew is safe.
__global__ __launch_bounds__(512, 2) void k_attn(const unsigned short* __restrict__ qb,
                                                 const unsigned short* __restrict__ kpk,
                                                 const unsigned short* __restrict__ vpk,
                                                 const int* __restrict__ mask,
                                                 unsigned short* __restrict__ ctx) {
  __shared__ float accS[4][32][32];
  __shared__ float lS[4][32];
  const int tid = threadIdx.x;
  const int lane = tid & 63;
  const int w = tid >> 6;
  const int qt = w >> 1, half = w & 1;
  const int l31 = lane & 31, hi = lane >> 5;
  const int q0 = blockIdx.x * 128 + qt * 32;
  const int h = blockIdx.y, b = blockIdx.z;
  const size_t bS = (size_t)b * S_;

  // phase skew: 0 / 128 / 256 / 384 cycles by wave pair
  switch (w & 3) {
    case 1: __builtin_amdgcn_s_sleep(2); break;
    case 2: __builtin_amdgcn_s_sleep(4); break;
    case 3: __builtin_amdgcn_s_sleep(6); break;
    default: break;
  }

  const unsigned short* Qp = qb + (bS + q0 + l31) * 256 + h * DK_ + hi * 8;
  short8 qf0 = *(const short8*)Qp;
  short8 qf1 = *(const short8*)(Qp + 16);

  const size_t fragbase = ((size_t)(b * H_ + h) * 64 + half * 32) * 2048 + lane * 8;
  const unsigned short* kp = kpk + fragbase;
  const unsigned short* vp = vpk + fragbase;
  const int* mp = mask + bS + half * 2048 + lane;

  f32x16 acc, lacc;
#pragma unroll
  for (int r = 0; r < 16; r++) { acc[r] = 0.f; lacc[r] = 0.f; }
  const f32x16 zz = acc;
  short8 ones;
#pragma unroll
  for (int e = 0; e < 8; e++) ones[e] = (short)0x3F80;

  short8 kf0, kf1, kf2, kf3, vf0, vf1, vf2, vf3;
  unsigned int pk0[8], pk1[8];
  f32x16 s0, s1;

#define LDKF() { kf0 = *(const short8*)(kp); kf1 = *(const short8*)(kp + 512); \
                 kf2 = *(const short8*)(kp + 1024); kf3 = *(const short8*)(kp + 1536); kp += 2048; }
#define LDVF() { vf0 = *(const short8*)(vp); vf1 = *(const short8*)(vp + 512); \
                 vf2 = *(const short8*)(vp + 1024); vf3 = *(const short8*)(vp + 1536); vp += 2048; }
#define QKM() {                                                                  \
    s0 = __builtin_amdgcn_mfma_f32_32x32x16_bf16(kf0, qf0, zz, 0, 0, 0);         \
    s1 = __builtin_amdgcn_mfma_f32_32x32x16_bf16(kf2, qf0, zz, 0, 0, 0);         \
    s0 = __builtin_amdgcn_mfma_f32_32x32x16_bf16(kf1, qf1, s0, 0, 0, 0);         \
    s1 = __builtin_amdgcn_mfma_f32_32x32x16_bf16(kf3, qf1, s1, 0, 0, 0);         \
  }
#define EXPM(mv) {                                                               \
    unsigned long long bal = __ballot((mv) != 0);                                \
    if (__builtin_expect(bal != ~0ull, 0)) {                                     \
      _Pragma("unroll") for (int r = 0; r < 16; r++) {                           \
        int tt = (r & 3) + 8 * (r >> 2) + 4 * hi;                                \
        if (!((bal >> tt) & 1)) s0[r] = -3e38f;                                  \
        if (!((bal >> (tt + 32)) & 1)) s1[r] = -3e38f;                           \
      }                                                                          \
    }                                                                            \
    _Pragma("unroll") for (int r = 0; r < 16; r++) {                             \
      s0[r] = __builtin_amdgcn_exp2f(s0[r]);                                     \
      s1[r] = __builtin_amdgcn_exp2f(s1[r]);                                     \
    }                                                                            \
    _Pragma("unroll") for (int j = 0; j < 8; j++) {                              \
      asm("v_cvt_pk_bf16_f32 %0, %1, %2" : "=v"(pk0[j]) : "v"(s0[2*j]), "v"(s0[2*j+1])); \
      asm("v_cvt_pk_bf16_f32 %0, %1, %2" : "=v"(pk1[j]) : "v"(s1[2*j]), "v"(s1[2*j+1])); \
    }                                                                            \
  }
#define PVM() {                                                                  \
    __builtin_amdgcn_s_setprio(1);                                               \
    _Pragma("unroll") for (int kk = 0; kk < 4; kk++) {                           \
      unsigned int* pk = (kk < 2) ? pk0 : pk1;                                   \
      int base = (kk & 1) * 4;                                                   \
      auto r02 = __builtin_amdgcn_permlane32_swap(pk[base], pk[base + 2], false, false);     \
      auto r13 = __builtin_amdgcn_permlane32_swap(pk[base + 1], pk[base + 3], false, false); \
      short8 pfr = u32x4_to_s8(r02[0], r13[0], r02[1], r13[1]);                  \
      short8 vv = (kk == 0) ? vf0 : (kk == 1) ? vf1 : (kk == 2) ? vf2 : vf3;     \
      acc = __builtin_amdgcn_mfma_f32_32x32x16_bf16(pfr, vv, acc, 0, 0, 0);      \
      lacc = __builtin_amdgcn_mfma_f32_32x32x16_bf16(pfr, ones, lacc, 0, 0, 0);  \
    }                                                                            \
    __builtin_amdgcn_s_setprio(0);                                               \
  }

  // prologue: tile 0
  LDKF();
  int mvC = mp[0];
  int mvN = mp[64];
  QKM();
  LDKF();
  LDVF();
  EXPM(mvC);
  mvC = mvN;
  mvN = mp[128];

  for (int t = 1; t < 32; ++t) {
    QKM();
    LDKF();
    PVM();
    LDVF();
    EXPM(mvC);
    mvC = mvN;
    mvN = mp[(t + 2 < 32 ? t + 2 : 31) * 64];
  }
  PVM();

  // 2-way merge across key-halves (plain sums; no-max softmax)
  if (half == 1) {
#pragma unroll
    for (int r = 0; r < 16; r++) {
      int q = (r & 3) + 8 * (r >> 2) + 4 * hi;
      accS[qt][q][l31] = acc[r];
    }
    if (l31 == 0) {
#pragma unroll
      for (int r = 0; r < 16; r++) {
        int q = (r & 3) + 8 * (r >> 2) + 4 * hi;
        lS[qt][q] = lacc[r];
      }
    }
  }
  __syncthreads();
  if (half == 0) {
#pragma unroll
    for (int r = 0; r < 16; r++) {
      int q = (r & 3) + 8 * (r >> 2) + 4 * hi;
      float o = acc[r] + accS[qt][q][l31];
      float L = lacc[r] + lS[qt][q];
      ctx[(bS + q0 + q) * (size_t)D_ + h * DK_ + l31] = f2bf(o / L);
    }
  }
#undef LDKF
#undef LDVF
#undef QKM
#undef EXPM
#undef PVM
}

extern "C" void kernel_launch(void* const* d_in, const int* in_sizes, int n_in,
                              void* d_out, int out_size, void* d_ws, size_t ws_size,
                              hipStream_t stream) {
  const float* x   = (const float*)d_in[0];
  const int* mask  = (const int*)d_in[1];
  const float* Wq  = (const float*)d_in[2];
  const float* bq  = (const float*)d_in[3];
  const float* Wk  = (const float*)d_in[4];
  const float* bk  = (const float*)d_in[5];
  const float* Wv  = (const float*)d_in[6];
  const float* bv  = (const float*)d_in[7];
  const float* Wo  = (const float*)d_in[8];
  const float* bo  = (const float*)d_in[9];
  const float* W1  = (const float*)d_in[10];
  const float* b1  = (const float*)d_in[11];
  const float* W2  = (const float*)d_in[12];
  const float* b2  = (const float*)d_in[13];
  const float* g1  = (const float*)d_in[14];
  const float* be1 = (const float*)d_in[15];
  const float* g2  = (const float*)d_in[16];
  const float* be2 = (const float*)d_in[17];
  const float* a1  = (const float*)d_in[18];
  const float* a2  = (const float*)d_in[19];
  float* out = (float*)d_out;

  char* ws = (char*)d_ws;
  const size_t MB = 1024 * 1024;
  unsigned short* qb  = (unsigned short*)(ws + 0);        // 4 MB
  unsigned short* kpk = (unsigned short*)(ws + 5 * MB);   // 4 MB
  unsigned short* vpk = (unsigned short*)(ws + 10 * MB);  // 4 MB
  unsigned short* ctx = (unsigned short*)(ws + 15 * MB);  // 4 MB
  unsigned short* x1b = (unsigned short*)(ws + 19 * MB);  // 4 MB
  unsigned short* hb  = (unsigned short*)(ws + 23 * MB);  // 16 MB
  unsigned short* WqkvT = (unsigned short*)(ws + 40 * MB);               // 384 KB
  unsigned short* WoT   = (unsigned short*)(ws + 40 * MB + 512 * 1024);  // 128 KB
  unsigned short* W1T   = (unsigned short*)(ws + 41 * MB);               // 512 KB
  unsigned short* W2T   = (unsigned short*)(ws + 41 * MB + 512 * 1024);  // 512 KB
  float* bqkv           = (float*)(ws + 42 * MB);                        // 3 KB
  unsigned short* xb    = (unsigned short*)(ws + 43 * MB);               // 4 MB

  const int NTOK = B_ * S_;  // 8192

  k_prepw<<<dim3(4099), 256, 0, stream>>>(Wq, Wk, Wv, Wo, W1, W2, bq, bk, bv, x,
                                          WqkvT, WoT, W1T, W2T, bqkv, xb);

  k_gemmqkv<<<dim3(64, 12), 256, 0, stream>>>(xb, WqkvT, bqkv, qb, kpk, vpk);

  k_attn<<<dim3(S_ / 128, H_, B_), 512, 0, stream>>>(qb, kpk, vpk, mask, ctx);

  // Wo GEMM + residual(x) + LN1 -> x1b (bf16)
  k_gemmln<0, 0><<<dim3(NTOK / 32), 512, 0, stream>>>(ctx, WoT, bo, x, a1, g1, be1,
                                                      x1b, 256);

  k_gemm1<<<dim3(64, 8), 256, 0, stream>>>(x1b, W1T, b1, hb, NTOK, 1024, 256);

  // W2 GEMM + residual(x1b) + LN2 -> out (f32)
  k_gemmln<1, 1><<<dim3(NTOK / 32), 512, 0, stream>>>(hb, W2T, b2, x1b, a2, g2, be2,
                                                      out, 1024);
}

// Round 13
// 129.520 us; speedup vs baseline: 1.0244x; 1.0244x over previous
//
#include <hip/hip_runtime.h>
#include <hip/hip_bf16.h>
#include <math.h>

#define B_ 2
#define S_ 4096
#define D_ 256
#define H_ 8
#define DFF_ 1024
#define DK_ 32

typedef __attribute__((ext_vector_type(8))) short short8;
typedef __attribute__((ext_vector_type(4))) float f32x4;
typedef __attribute__((ext_vector_type(16))) float f32x16;
typedef __attribute__((ext_vector_type(4))) int int4v;

__device__ __forceinline__ unsigned short f2bf(float f) {
  unsigned int u = __builtin_bit_cast(unsigned int, f);
  u += 0x7FFFu + ((u >> 16) & 1u);
  return (unsigned short)(u >> 16);
}

__device__ __forceinline__ float bf2f(unsigned short s) {
  unsigned int u = ((unsigned int)s) << 16;
  return __builtin_bit_cast(float, u);
}

__device__ __forceinline__ short8 u32x4_to_s8(unsigned int a, unsigned int b,
                                              unsigned int c, unsigned int d) {
  int4v v = {(int)a, (int)b, (int)c, (int)d};
  return __builtin_bit_cast(short8, v);
}

// ---------------- fused prep: weight transpose+convert, x->bf16 --------------
__global__ __launch_bounds__(256) void k_prepw(
    const float* __restrict__ Wq, const float* __restrict__ Wk,
    const float* __restrict__ Wv, const float* __restrict__ Wo,
    const float* __restrict__ W1, const float* __restrict__ W2,
    const float* __restrict__ bq, const float* __restrict__ bk,
    const float* __restrict__ bv, const float* __restrict__ x,
    unsigned short* __restrict__ WqkvT, unsigned short* __restrict__ WoT,
    unsigned short* __restrict__ W1T, unsigned short* __restrict__ W2T,
    float* __restrict__ bqkv, unsigned short* __restrict__ xb) {
  const float k2 = 0.25500525551f;  // log2(e)/sqrt(DK)
  int bx = blockIdx.x, t = threadIdx.x;
  if (bx < 768) {
    int which = bx >> 8;
    int i = ((bx & 255) << 8) | t;
    const float* W = (which == 0) ? Wq : (which == 1) ? Wk : Wv;
    int n = i >> 8, k = i & 255;
    float v = W[k * 256 + n] * ((which == 0) ? k2 : 1.0f);
    WqkvT[(size_t)(which * 256 + n) * 256 + k] = f2bf(v);
  } else if (bx < 1024) {
    int i = ((bx - 768) << 8) | t;
    int n = i >> 8, k = i & 255;
    WoT[i] = f2bf(Wo[k * 256 + n]);
  } else if (bx < 2048) {
    int i = ((bx - 1024) << 8) | t;
    int n = i >> 8, k = i & 255;
    W1T[i] = f2bf(W1[k * 1024 + n]);
  } else if (bx < 3072) {
    int i = ((bx - 2048) << 8) | t;
    int n = i >> 10, k = i & 1023;
    W2T[i] = f2bf(W2[k * 256 + n]);
  } else if (bx < 3075) {
    int i = ((bx - 3072) << 8) | t;
    if (i < 768) bqkv[i] = (i < 256) ? bq[i] * k2 : (i < 512) ? bk[i - 256] : bv[i - 512];
  } else {
    int i = (bx - 3075) * 2048 + t * 8;
    f32x4 f0 = *(const f32x4*)(x + i);
    f32x4 f1 = *(const f32x4*)(x + i + 4);
    short8 o;
#pragma unroll
    for (int e = 0; e < 4; e++) { o[e] = (short)f2bf(f0[e]); o[e + 4] = (short)f2bf(f1[e]); }
    *(short8*)(xb + i) = o;
  }
}

// ---------------- QKV GEMM with fragment-scatter epilogue --------------------
__global__ __launch_bounds__(256) void k_gemmqkv(const unsigned short* __restrict__ A,
                                                 const unsigned short* __restrict__ Bt,
                                                 const float* __restrict__ bias,
                                                 unsigned short* __restrict__ qb,
                                                 unsigned short* __restrict__ kpk,
                                                 unsigned short* __restrict__ vpk) {
  const int K = 256;
  __shared__ unsigned short Al[128][40];
  __shared__ unsigned short Bl[64][40];
  const int tid = threadIdx.x;
  const int wid = tid >> 6, lane = tid & 63;
  const int lhi = lane >> 4, llo = lane & 15;
  const int rowbase = wid * 32;
  const int bm = blockIdx.x, bn = blockIdx.y;

  f32x4 zero = {0.f, 0.f, 0.f, 0.f};
  f32x4 acc[2][4];
#pragma unroll
  for (int m = 0; m < 2; m++)
#pragma unroll
    for (int n = 0; n < 4; n++) acc[m][n] = zero;

  const int r0 = tid >> 2, c8 = (tid & 3) * 8;
  const unsigned short* A16a = A + (size_t)(bm * 128 + r0) * K + c8;
  const unsigned short* A16b = A + (size_t)(bm * 128 + r0 + 64) * K + c8;
  const unsigned short* Brow0 = Bt + (size_t)(bn * 64 + r0) * K + c8;

  for (int kb = 0; kb < K; kb += 32) {
    __syncthreads();
    *(short8*)&Al[r0][c8] = *(const short8*)(A16a + kb);
    *(short8*)&Al[r0 + 64][c8] = *(const short8*)(A16b + kb);
    *(short8*)&Bl[r0][c8] = *(const short8*)(Brow0 + kb);
    __syncthreads();
    short8 af[2], bf[4];
#pragma unroll
    for (int m = 0; m < 2; m++) af[m] = *(const short8*)&Al[rowbase + m * 16 + llo][lhi * 8];
#pragma unroll
    for (int n = 0; n < 4; n++) bf[n] = *(const short8*)&Bl[n * 16 + llo][lhi * 8];
#pragma unroll
    for (int m = 0; m < 2; m++)
#pragma unroll
      for (int n = 0; n < 4; n++)
        acc[m][n] = __builtin_amdgcn_mfma_f32_16x16x32_bf16(af[m], bf[n], acc[m][n], 0, 0, 0);
  }

  const int which = bn >> 2;  // 0=Q, 1=K, 2=V
#pragma unroll
  for (int m = 0; m < 2; m++)
#pragma unroll
    for (int n = 0; n < 4; n++)
#pragma unroll
      for (int r = 0; r < 4; r++) {
        int row = bm * 128 + rowbase + m * 16 + lhi * 4 + r;
        int gcol = bn * 64 + n * 16 + llo;
        int col0 = gcol - which * 256;
        float v = acc[m][n][r] + bias[gcol];
        unsigned short bv = f2bf(v);
        int t = row & (S_ - 1), b = row >> 12;
        int h = col0 >> 5;
        if (which == 0) {
          qb[(size_t)row * 256 + col0] = bv;
        } else if (which == 1) {
          int c5 = col0 & 31, jj = (c5 >> 4) & 1, hik = (c5 >> 3) & 1, e = c5 & 7;
          int tile = t >> 6, i = (t >> 5) & 1, l31k = t & 31;
          size_t addr = (((size_t)(b * 8 + h) * 64 + tile) * 4 + i * 2 + jj) * 512 +
                        (hik * 32 + l31k) * 8 + e;
          kpk[addr] = bv;
        } else {
          int d = col0 & 31;
          int x5 = t >> 6, j = (t >> 3) & 7, kk = t & 7;
          size_t addr = (((size_t)(b * 8 + h) * 64 + x5) * 4 + (j >> 1)) * 512 +
                        ((j & 1) * 32 + d) * 8 + kk;
          vpk[addr] = bv;
        }
      }
}

// ---------------- bf16 GEMM (FFN1): C = GELU(A @ Bt^T + bias), bf16 out ------
__global__ __launch_bounds__(256) void k_gemm1(const unsigned short* __restrict__ A,
                                               const unsigned short* __restrict__ Bt,
                                               const float* __restrict__ bias,
                                               unsigned short* __restrict__ Cout,
                                               int M, int N, int K) {
  __shared__ unsigned short Al[128][40];
  __shared__ unsigned short Bl[128][40];
  const int tid = threadIdx.x;
  const int wid = tid >> 6, lane = tid & 63;
  const int lhi = lane >> 4, llo = lane & 15;
  const int wr = wid >> 1, wc = wid & 1;
  const int rowbase = wr * 64, colbase = wc * 64;
  const int bm = blockIdx.x, bn = blockIdx.y;

  f32x4 zero = {0.f, 0.f, 0.f, 0.f};
  f32x4 acc[4][4];
#pragma unroll
  for (int m = 0; m < 4; m++)
#pragma unroll
    for (int n = 0; n < 4; n++) acc[m][n] = zero;

  const int r0 = tid >> 2, c8 = (tid & 3) * 8;
  const unsigned short* A16a = A + (size_t)(bm * 128 + r0) * K + c8;
  const unsigned short* A16b = A + (size_t)(bm * 128 + r0 + 64) * K + c8;
  const unsigned short* Brow0 = Bt + (size_t)(bn * 128 + r0) * K + c8;
  const unsigned short* Brow1 = Bt + (size_t)(bn * 128 + r0 + 64) * K + c8;

  for (int kb = 0; kb < K; kb += 32) {
    __syncthreads();
    *(short8*)&Al[r0][c8] = *(const short8*)(A16a + kb);
    *(short8*)&Al[r0 + 64][c8] = *(const short8*)(A16b + kb);
    *(short8*)&Bl[r0][c8] = *(const short8*)(Brow0 + kb);
    *(short8*)&Bl[r0 + 64][c8] = *(const short8*)(Brow1 + kb);
    __syncthreads();
    short8 af[4], bf[4];
#pragma unroll
    for (int m = 0; m < 4; m++) af[m] = *(const short8*)&Al[rowbase + m * 16 + llo][lhi * 8];
#pragma unroll
    for (int n = 0; n < 4; n++) bf[n] = *(const short8*)&Bl[colbase + n * 16 + llo][lhi * 8];
#pragma unroll
    for (int m = 0; m < 4; m++)
#pragma unroll
      for (int n = 0; n < 4; n++)
        acc[m][n] = __builtin_amdgcn_mfma_f32_16x16x32_bf16(af[m], bf[n], acc[m][n], 0, 0, 0);
  }

#pragma unroll
  for (int m = 0; m < 4; m++)
#pragma unroll
    for (int n = 0; n < 4; n++)
#pragma unroll
      for (int r = 0; r < 4; r++) {
        int row = bm * 128 + rowbase + m * 16 + lhi * 4 + r;
        int col = bn * 128 + colbase + n * 16 + llo;
        float v = acc[m][n][r] + bias[col];
        v = 0.5f * v * (1.0f + erff(v * 0.70710678118f));
        Cout[(size_t)row * N + col] = f2bf(v);
      }
}

// ---------------- GEMM + residual + LayerNorm fused, split-K-2 ---------------
template <int BASE16, int OUT32>
__global__ __launch_bounds__(512) void k_gemmln(const unsigned short* __restrict__ A,
                                                const unsigned short* __restrict__ Bt,
                                                const float* __restrict__ bias,
                                                const void* __restrict__ base,
                                                const float* __restrict__ alpha,
                                                const float* __restrict__ g,
                                                const float* __restrict__ be,
                                                void* __restrict__ y, int K) {
  __shared__ unsigned short Al[2][32][40];
  __shared__ unsigned short Bl[2][256][40];
  __shared__ float psum[32][4], psq[32][4];
  float* partial = (float*)&Bl[0][0][0];

  const int tid = threadIdx.x;
  const int w = tid >> 6, lane = tid & 63;
  const int kh = w >> 2, wc = w & 3;
  const int lhi = lane >> 4, llo = lane & 15;
  const int row0 = blockIdx.x * 32;
  const int Kh = K >> 1;

  f32x4 zero = {0.f, 0.f, 0.f, 0.f};
  f32x4 acc[2][4];
#pragma unroll
  for (int m = 0; m < 2; m++)
#pragma unroll
    for (int n = 0; n < 4; n++) acc[m][n] = zero;

  for (int kb = 0; kb < Kh; kb += 32) {
    __syncthreads();
    if (tid < 256) {
      int kh2 = tid >> 7, ra = (tid >> 2) & 31, ca = (tid & 3) * 8;
      *(short8*)&Al[kh2][ra][ca] =
          *(const short8*)(A + (size_t)(row0 + ra) * K + kh2 * Kh + kb + ca);
    }
#pragma unroll
    for (int s = 0; s < 4; s++) {
      int c = tid + s * 512;
      int kh2 = c >> 10, rb = (c >> 2) & 255, cb = (c & 3) * 8;
      *(short8*)&Bl[kh2][rb][cb] =
          *(const short8*)(Bt + (size_t)rb * K + kh2 * Kh + kb + cb);
    }
    __syncthreads();
    short8 af[2], bf[4];
#pragma unroll
    for (int m = 0; m < 2; m++) af[m] = *(const short8*)&Al[kh][m * 16 + llo][lhi * 8];
#pragma unroll
    for (int n = 0; n < 4; n++)
      bf[n] = *(const short8*)&Bl[kh][wc * 64 + n * 16 + llo][lhi * 8];
#pragma unroll
    for (int m = 0; m < 2; m++)
#pragma unroll
      for (int n = 0; n < 4; n++)
        acc[m][n] = __builtin_amdgcn_mfma_f32_16x16x32_bf16(af[m], bf[n], acc[m][n], 0, 0, 0);
  }

  __syncthreads();
  if (kh == 1) {
#pragma unroll
    for (int m = 0; m < 2; m++)
#pragma unroll
      for (int n = 0; n < 4; n++)
#pragma unroll
        for (int r = 0; r < 4; r++) {
          int lrow = m * 16 + lhi * 4 + r;
          int col = wc * 64 + n * 16 + llo;
          partial[lrow * 256 + col] = acc[m][n][r];
        }
  }
  __syncthreads();

  const float a = alpha[0];
  const unsigned short* b16 = (const unsigned short*)base;
  const float* b32 = (const float*)base;

  if (kh == 0) {
#pragma unroll
    for (int m = 0; m < 2; m++)
#pragma unroll
      for (int r = 0; r < 4; r++) {
        int lrow = m * 16 + lhi * 4 + r;
        size_t grow = (size_t)(row0 + lrow);
        float s = 0.f, q = 0.f;
#pragma unroll
        for (int n = 0; n < 4; n++) {
          int col = wc * 64 + n * 16 + llo;
          float v = acc[m][n][r] + partial[lrow * 256 + col] + bias[col];
          float xb = BASE16 ? bf2f(b16[grow * 256 + col]) : b32[grow * 256 + col];
          float rr = fmaf(a, v, xb);
          acc[m][n][r] = rr;
          s += rr;
          q = fmaf(rr, rr, q);
        }
#pragma unroll
        for (int off = 1; off < 16; off <<= 1) {
          s += __shfl_xor(s, off);
          q += __shfl_xor(q, off);
        }
        if (llo == 0) { psum[lrow][wc] = s; psq[lrow][wc] = q; }
      }
  }
  __syncthreads();

  if (kh == 0) {
#pragma unroll
    for (int m = 0; m < 2; m++)
#pragma unroll
      for (int r = 0; r < 4; r++) {
        int lrow = m * 16 + lhi * 4 + r;
        size_t grow = (size_t)(row0 + lrow);
        float S = psum[lrow][0] + psum[lrow][1] + psum[lrow][2] + psum[lrow][3];
        float Q = psq[lrow][0] + psq[lrow][1] + psq[lrow][2] + psq[lrow][3];
        float mu = S * (1.0f / 256.0f);
        float var = Q * (1.0f / 256.0f) - mu * mu;
        float rs = rsqrtf(var + 1e-5f);
#pragma unroll
        for (int n = 0; n < 4; n++) {
          int col = wc * 64 + n * 16 + llo;
          float o = (acc[m][n][r] - mu) * rs * g[col] + be[col];
          if (OUT32) ((float*)y)[grow * 256 + col] = o;
          else ((unsigned short*)y)[grow * 256 + col] = f2bf(o);
        }
      }
  }
}

// ---------------- flash attention: 4 waves = 4 key-quarters, 64 q-rows/wave --
// Each wave amortizes the 8 KB K/V tile over TWO 32-q subtiles (A/B), halving
// L1 bytes per score (round-12 analysis: L1 port was ~86% busy at 32 q/wave).
__global__ __launch_bounds__(256, 3) void k_attn(const unsigned short* __restrict__ qbuf,
                                                 const unsigned short* __restrict__ kpk,
                                                 const unsigned short* __restrict__ vpk,
                                                 const int* __restrict__ mask,
                                                 unsigned short* __restrict__ ctx) {
  __shared__ float accS[4][64][32];  // 32 KB
  __shared__ float lS[4][64];
  const int tid = threadIdx.x;
  const int lane = tid & 63;
  const int w = tid >> 6;            // key quarter
  const int l31 = lane & 31, hi = lane >> 5;
  const int q0 = blockIdx.x * 64;
  const int h = blockIdx.y, b = blockIdx.z;
  const size_t bS = (size_t)b * S_;

  const unsigned short* QpA = qbuf + (bS + q0 + l31) * 256 + h * DK_ + hi * 8;
  short8 qa0 = *(const short8*)QpA;
  short8 qa1 = *(const short8*)(QpA + 16);
  const unsigned short* QpB = QpA + 32 * 256;
  short8 qb0 = *(const short8*)QpB;
  short8 qb1 = *(const short8*)(QpB + 16);

  const size_t fragbase = ((size_t)(b * H_ + h) * 64 + w * 16) * 2048 + lane * 8;
  const unsigned short* kp = kpk + fragbase;
  const unsigned short* vp = vpk + fragbase;
  const int* mp = mask + bS + w * 1024 + lane;

  f32x16 accA, accB, laccA, laccB;
#pragma unroll
  for (int r = 0; r < 16; r++) { accA[r] = 0.f; accB[r] = 0.f; laccA[r] = 0.f; laccB[r] = 0.f; }
  const f32x16 zz = accA;
  short8 ones;
#pragma unroll
  for (int e = 0; e < 8; e++) ones[e] = (short)0x3F80;

  short8 kf0, kf1, kf2, kf3, vf0, vf1, vf2, vf3;
  unsigned int pk0[8], pk1[8];
  f32x16 s0, s1;

#define LDKF() { kf0 = *(const short8*)(kp); kf1 = *(const short8*)(kp + 512); \
                 kf2 = *(const short8*)(kp + 1024); kf3 = *(const short8*)(kp + 1536); kp += 2048; }
#define LDVF() { vf0 = *(const short8*)(vp); vf1 = *(const short8*)(vp + 512); \
                 vf2 = *(const short8*)(vp + 1024); vf3 = *(const short8*)(vp + 1536); vp += 2048; }
#define QKM(qx0, qx1) {                                                          \
    s0 = __builtin_amdgcn_mfma_f32_32x32x16_bf16(kf0, qx0, zz, 0, 0, 0);         \
    s1 = __builtin_amdgcn_mfma_f32_32x32x16_bf16(kf2, qx0, zz, 0, 0, 0);         \
    s0 = __builtin_amdgcn_mfma_f32_32x32x16_bf16(kf1, qx1, s0, 0, 0, 0);         \
    s1 = __builtin_amdgcn_mfma_f32_32x32x16_bf16(kf3, qx1, s1, 0, 0, 0);         \
  }
#define EXPM(bal) {                                                              \
    if (__builtin_expect((bal) != ~0ull, 0)) {                                   \
      _Pragma("unroll") for (int r = 0; r < 16; r++) {                           \
        int tt = (r & 3) + 8 * (r >> 2) + 4 * hi;                                \
        if (!(((bal) >> tt) & 1)) s0[r] = -3e38f;                                \
        if (!(((bal) >> (tt + 32)) & 1)) s1[r] = -3e38f;                         \
      }                                                                          \
    }                                                                            \
    _Pragma("unroll") for (int r = 0; r < 16; r++) {                             \
      s0[r] = __builtin_amdgcn_exp2f(s0[r]);                                     \
      s1[r] = __builtin_amdgcn_exp2f(s1[r]);                                     \
    }                                                                            \
    _Pragma("unroll") for (int j = 0; j < 8; j++) {                              \
      asm("v_cvt_pk_bf16_f32 %0, %1, %2" : "=v"(pk0[j]) : "v"(s0[2*j]), "v"(s0[2*j+1])); \
      asm("v_cvt_pk_bf16_f32 %0, %1, %2" : "=v"(pk1[j]) : "v"(s1[2*j]), "v"(s1[2*j+1])); \
    }                                                                            \
  }
#define PVM(accX, laccX) {                                                       \
    __builtin_amdgcn_s_setprio(1);                                               \
    _Pragma("unroll") for (int kk = 0; kk < 4; kk++) {                           \
      unsigned int* pk = (kk < 2) ? pk0 : pk1;                                   \
      int base = (kk & 1) * 4;                                                   \
      auto r02 = __builtin_amdgcn_permlane32_swap(pk[base], pk[base + 2], false, false);     \
      auto r13 = __builtin_amdgcn_permlane32_swap(pk[base + 1], pk[base + 3], false, false); \
      short8 pfr = u32x4_to_s8(r02[0], r13[0], r02[1], r13[1]);                  \
      short8 vv = (kk == 0) ? vf0 : (kk == 1) ? vf1 : (kk == 2) ? vf2 : vf3;     \
      accX = __builtin_amdgcn_mfma_f32_32x32x16_bf16(pfr, vv, accX, 0, 0, 0);    \
      laccX = __builtin_amdgcn_mfma_f32_32x32x16_bf16(pfr, ones, laccX, 0, 0, 0);\
    }                                                                            \
    __builtin_amdgcn_s_setprio(0);                                               \
  }

  LDKF();   // K(0)
  LDVF();   // V(0)
  int mvC = mp[0];
  int mvN = mp[64];

  for (int t = 0; t < 16; ++t) {
    unsigned long long bal = __ballot(mvC != 0);
    QKM(qa0, qa1);
    EXPM(bal);
    PVM(accA, laccA);
    QKM(qb0, qb1);
    LDKF();           // K(t+1); final iter over-reads into slack (unused)
    EXPM(bal);
    PVM(accB, laccB);
    LDVF();           // V(t+1)
    mvC = mvN;
    mvN = mp[(t + 2 < 16 ? t + 2 : 15) * 64];
  }

  // 4-way merge across key-quarters (plain sums; no-max softmax)
#pragma unroll
  for (int r = 0; r < 16; r++) {
    int q = (r & 3) + 8 * (r >> 2) + 4 * hi;
    accS[w][q][l31] = accA[r];
    accS[w][q + 32][l31] = accB[r];
  }
  if (l31 == 0) {
#pragma unroll
    for (int r = 0; r < 16; r++) {
      int q = (r & 3) + 8 * (r >> 2) + 4 * hi;
      lS[w][q] = laccA[r];
      lS[w][q + 32] = laccB[r];
    }
  }
  __syncthreads();
#pragma unroll
  for (int i = 0; i < 8; i++) {
    int e = tid + 256 * i;
    int q = e >> 5, d = e & 31;
    float o = accS[0][q][d] + accS[1][q][d] + accS[2][q][d] + accS[3][q][d];
    float L = lS[0][q] + lS[1][q] + lS[2][q] + lS[3][q];
    ctx[(bS + q0 + q) * (size_t)D_ + h * DK_ + d] = f2bf(o / L);
  }
#undef LDKF
#undef LDVF
#undef QKM
#undef EXPM
#undef PVM
}

extern "C" void kernel_launch(void* const* d_in, const int* in_sizes, int n_in,
                              void* d_out, int out_size, void* d_ws, size_t ws_size,
                              hipStream_t stream) {
  const float* x   = (const float*)d_in[0];
  const int* mask  = (const int*)d_in[1];
  const float* Wq  = (const float*)d_in[2];
  const float* bq  = (const float*)d_in[3];
  const float* Wk  = (const float*)d_in[4];
  const float* bk  = (const float*)d_in[5];
  const float* Wv  = (const float*)d_in[6];
  const float* bv  = (const float*)d_in[7];
  const float* Wo  = (const float*)d_in[8];
  const float* bo  = (const float*)d_in[9];
  const float* W1  = (const float*)d_in[10];
  const float* b1  = (const float*)d_in[11];
  const float* W2  = (const float*)d_in[12];
  const float* b2  = (const float*)d_in[13];
  const float* g1  = (const float*)d_in[14];
  const float* be1 = (const float*)d_in[15];
  const float* g2  = (const float*)d_in[16];
  const float* be2 = (const float*)d_in[17];
  const float* a1  = (const float*)d_in[18];
  const float* a2  = (const float*)d_in[19];
  float* out = (float*)d_out;

  char* ws = (char*)d_ws;
  const size_t MB = 1024 * 1024;
  unsigned short* qb  = (unsigned short*)(ws + 0);        // 4 MB
  unsigned short* kpk = (unsigned short*)(ws + 5 * MB);   // 4 MB (+1 MB slack)
  unsigned short* vpk = (unsigned short*)(ws + 10 * MB);  // 4 MB (+1 MB slack)
  unsigned short* ctx = (unsigned short*)(ws + 15 * MB);  // 4 MB
  unsigned short* x1b = (unsigned short*)(ws + 19 * MB);  // 4 MB
  unsigned short* hb  = (unsigned short*)(ws + 23 * MB);  // 16 MB
  unsigned short* WqkvT = (unsigned short*)(ws + 40 * MB);               // 384 KB
  unsigned short* WoT   = (unsigned short*)(ws + 40 * MB + 512 * 1024);  // 128 KB
  unsigned short* W1T   = (unsigned short*)(ws + 41 * MB);               // 512 KB
  unsigned short* W2T   = (unsigned short*)(ws + 41 * MB + 512 * 1024);  // 512 KB
  float* bqkv           = (float*)(ws + 42 * MB);                        // 3 KB
  unsigned short* xb    = (unsigned short*)(ws + 43 * MB);               // 4 MB

  const int NTOK = B_ * S_;  // 8192

  k_prepw<<<dim3(4099), 256, 0, stream>>>(Wq, Wk, Wv, Wo, W1, W2, bq, bk, bv, x,
                                          WqkvT, WoT, W1T, W2T, bqkv, xb);

  k_gemmqkv<<<dim3(64, 12), 256, 0, stream>>>(xb, WqkvT, bqkv, qb, kpk, vpk);

  k_attn<<<dim3(S_ / 64, H_, B_), 256, 0, stream>>>(qb, kpk, vpk, mask, ctx);

  // Wo GEMM + residual(x) + LN1 -> x1b (bf16)
  k_gemmln<0, 0><<<dim3(NTOK / 32), 512, 0, stream>>>(ctx, WoT, bo, x, a1, g1, be1,
                                                      x1b, 256);

  k_gemm1<<<dim3(64, 8), 256, 0, stream>>>(x1b, W1T, b1, hb, NTOK, 1024, 256);

  // W2 GEMM + residual(x1b) + LN2 -> out (f32)
  k_gemmln<1, 1><<<dim3(NTOK / 32), 512, 0, stream>>>(hb, W2T, b2, x1b, a2, g2, be2,
                                                      out, 1024);
}